// Round 7
// baseline (300.906 us; speedup 1.0000x reference)
//
#include <hip/hip_runtime.h>
#include <hip/hip_bf16.h>
#include <stdint.h>

// SelfAttention B=2,T=2048,C=1024,H=16,hd=64.
// R7 ROOT-CAUSE FIX: d_out is FP32 (proven by R6 poke-invisibility + R3..R6
// bit-identical absmax). Inputs are fp32 holding bf16-rounded values.
// Pipeline (all MFMA stages HW-verified equivalent via R3==R4==R5):
//   0. detect per-input dtype (defensive; expected fp32)
//   1. convert x -> bf16 xb; biases -> fp32 ws copies
//   2. transpose+convert w_qkv -> wqkvT bf16, w_out -> woutT bf16
//   3. gemm_bt (MFMA bf16): qkv = xb @ w_qkv + b_qkv  (bf16, ws)
//   4. MFMA flash attention (causal, online softmax) -> Y (bf16, ws)
//   5. gemm_bt_f32out (MFMA bf16, FP32 store): out = Y @ w_out + b_out

typedef __bf16 bf16_t;
typedef __attribute__((ext_vector_type(8))) __bf16 bf16x8;
typedef __attribute__((ext_vector_type(4))) float f32x4;

static_assert(sizeof(bf16x8) == 16, "bf16x8 must be 16B");

// ---------------------------------------------------------------------------
__global__ void zs_kernel_r7(int* st) {
  if (threadIdx.x < 16) st[threadIdx.x] = 0;
}

// block 0: x (stride 1024), block 1: w_qkv (768), block 2: w_out (256).
// Samples stay inside the buffer under BOTH dtype interpretations.
__global__ __launch_bounds__(256) void detect3_kernel_r7(
    const uint32_t* __restrict__ x, const uint32_t* __restrict__ wq,
    const uint32_t* __restrict__ wo, int* __restrict__ st) {
  __shared__ int cnt[256];
  const uint32_t* p;
  int stride;
  if (blockIdx.x == 0) { p = x;  stride = 1024; }
  else if (blockIdx.x == 1) { p = wq; stride = 768; }
  else { p = wo; stride = 256; }
  int c = 0;
#pragma unroll
  for (int i = 0; i < 8; i++) {
    uint32_t w = p[(size_t)(threadIdx.x * 8 + i) * stride];
    int e = (w >> 7) & 0xff;  // exponent of the LOW half viewed as bf16
    c += (e >= 100 && e <= 134) ? 1 : 0;
  }
  cnt[threadIdx.x] = c;
  __syncthreads();
  for (int s = 128; s > 0; s >>= 1) {
    if (threadIdx.x < s) cnt[threadIdx.x] += cnt[threadIdx.x + s];
    __syncthreads();
  }
  if (threadIdx.x == 0) st[blockIdx.x] = (cnt[0] > 1228) ? 1 : 0;
}

// ---------------------------------------------------------------------------
// x -> bf16, 8 elems/thread. flag: 1 = src already bf16, 0 = fp32.
__global__ __launch_bounds__(256) void convx_kernel_r7(
    const void* __restrict__ src, bf16_t* __restrict__ dst, int n8,
    const int* __restrict__ st) {
  const int i = blockIdx.x * 256 + threadIdx.x;
  if (i >= n8) return;
  if (st[0]) {
    ((bf16x8*)dst)[i] = ((const bf16x8*)src)[i];
  } else {
    const float4* s = (const float4*)src;
    float4 a = s[i * 2], b = s[i * 2 + 1];
    bf16x8 o;
    o[0] = (bf16_t)a.x; o[1] = (bf16_t)a.y; o[2] = (bf16_t)a.z; o[3] = (bf16_t)a.w;
    o[4] = (bf16_t)b.x; o[5] = (bf16_t)b.y; o[6] = (bf16_t)b.z; o[7] = (bf16_t)b.w;
    ((bf16x8*)dst)[i] = o;
  }
}

// biases -> fp32 ws copies. Uses the matching weight's flag as dtype proxy.
__global__ __launch_bounds__(256) void convbias_kernel_r7(
    const void* __restrict__ bq, const void* __restrict__ bo,
    float* __restrict__ bqf, float* __restrict__ bof,
    const int* __restrict__ st) {
  const int i = blockIdx.x * 256 + threadIdx.x;
  if (i < 3072)
    bqf[i] = st[1] ? (float)((const bf16_t*)bq)[i] : ((const float*)bq)[i];
  if (i < 1024)
    bof[i] = st[2] ? (float)((const bf16_t*)bo)[i] : ((const float*)bo)[i];
}

// ---------------------------------------------------------------------------
// Transpose+convert: out[c][r] = (bf16)in[r][c]. in is R x C. flag slot fi.
__global__ __launch_bounds__(256) void transconv_kernel_r7(
    const void* __restrict__ in, bf16_t* __restrict__ out, int R, int C,
    const int* __restrict__ st, int fi) {
  __shared__ bf16_t tile[32][33];
  const int c0 = blockIdx.x * 32, r0 = blockIdx.y * 32;
  const int tx = threadIdx.x & 31;
  const int ty = threadIdx.x >> 5;
  const bool isbf = (st[fi] != 0);
#pragma unroll
  for (int i = 0; i < 4; i++) {
    int r = ty + i * 8;
    size_t idx = (size_t)(r0 + r) * C + c0 + tx;
    tile[r][tx] = isbf ? ((const bf16_t*)in)[idx] : (bf16_t)((const float*)in)[idx];
  }
  __syncthreads();
#pragma unroll
  for (int i = 0; i < 4; i++) {
    int r = ty + i * 8;
    out[(size_t)(c0 + r) * R + r0 + tx] = tile[tx][r];
  }
}

// ---------------------------------------------------------------------------
// C[M,N] = A[M,K] @ Bt[N,K]^T + bias[N]. bf16 in, OUT_F32 selects store type.
// BM=BN=128, BK=32, 4 waves 2x2, grid (N/128, M/128). HW-verified structure.
// ---------------------------------------------------------------------------
template <bool OUT_F32>
__global__ __launch_bounds__(256) void gemm_bt_kernel_r7(
    const bf16_t* __restrict__ A, const bf16_t* __restrict__ Bt,
    const float* __restrict__ bias, void* __restrict__ Cv, int M, int N,
    int K) {
  __shared__ __align__(16) bf16_t sA[128 * 32];
  __shared__ __align__(16) bf16_t sB[128 * 32];
  const int tid = threadIdx.x;
  const int wave = tid >> 6, lane = tid & 63;
  const int quad = lane >> 4, l16 = lane & 15;
  const int wm = (wave >> 1) * 64, wn = (wave & 1) * 64;
  const int bm = blockIdx.y * 128, bn = blockIdx.x * 128;

  const int srow = tid >> 2;
  const int skk = (tid & 3) * 8;
  const bf16_t* gA0 = A + (size_t)(bm + srow) * K + skk;
  const bf16_t* gA1 = A + (size_t)(bm + srow + 64) * K + skk;
  const bf16_t* gB0 = Bt + (size_t)(bn + srow) * K + skk;
  const bf16_t* gB1 = Bt + (size_t)(bn + srow + 64) * K + skk;

  f32x4 acc[4][4] = {};

  for (int k0 = 0; k0 < K; k0 += 32) {
    bf16x8 a0 = *(const bf16x8*)(gA0 + k0);
    bf16x8 a1 = *(const bf16x8*)(gA1 + k0);
    bf16x8 b0 = *(const bf16x8*)(gB0 + k0);
    bf16x8 b1 = *(const bf16x8*)(gB1 + k0);
    __syncthreads();
    *(bf16x8*)&sA[srow * 32 + skk] = a0;
    *(bf16x8*)&sA[(srow + 64) * 32 + skk] = a1;
    *(bf16x8*)&sB[srow * 32 + skk] = b0;
    *(bf16x8*)&sB[(srow + 64) * 32 + skk] = b1;
    __syncthreads();

    bf16x8 af[4], bfr[4];
#pragma unroll
    for (int i = 0; i < 4; i++)
      af[i] = *(const bf16x8*)&sA[(wm + i * 16 + l16) * 32 + quad * 8];
#pragma unroll
    for (int j = 0; j < 4; j++)
      bfr[j] = *(const bf16x8*)&sB[(wn + j * 16 + l16) * 32 + quad * 8];
#pragma unroll
    for (int i = 0; i < 4; i++)
#pragma unroll
      for (int j = 0; j < 4; j++)
        acc[i][j] = __builtin_amdgcn_mfma_f32_16x16x32_bf16(af[i], bfr[j],
                                                            acc[i][j], 0, 0, 0);
  }

#pragma unroll
  for (int j = 0; j < 4; j++) {
    const int col = bn + wn + j * 16 + l16;
    const float bv = bias[col];
#pragma unroll
    for (int i = 0; i < 4; i++) {
#pragma unroll
      for (int r = 0; r < 4; r++) {
        const int row = bm + wm + i * 16 + quad * 4 + r;
        const float v = acc[i][j][r] + bv;
        if (OUT_F32)
          ((float*)Cv)[(size_t)row * N + col] = v;
        else
          ((bf16_t*)Cv)[(size_t)row * N + col] = (bf16_t)v;
      }
    }
  }
}

// ---------------------------------------------------------------------------
// MFMA flash attention, causal (HW-verified == naive via R3==R4).
// qkv: [(b*T+t)*3072 + s*1024 + h*64 + d]; Y: [(b*T+t)*1024 + h*64 + d].
// grid (T/64, B*H), 256 threads; wave owns 16 q-rows; K-tiles of 64.
// ---------------------------------------------------------------------------
__global__ __launch_bounds__(256) void attn_kernel_r7(
    const bf16_t* __restrict__ qkv, bf16_t* __restrict__ Y) {
  constexpr int T = 2048, C3 = 3072;
  constexpr float NEG = -30000.0f;
  __shared__ __align__(16) bf16_t sK[64 * 72];
  __shared__ __align__(16) bf16_t sVt[64 * 72];
  __shared__ __align__(16) bf16_t sP[4][16 * 72];

  const int tid = threadIdx.x;
  const int wave = tid >> 6, lane = tid & 63;
  const int quad = lane >> 4, l16 = lane & 15;
  const int q0 = blockIdx.x * 64;
  const int bh = blockIdx.y;
  const int b = bh >> 4, h = bh & 15;
  const size_t base = (size_t)b * T * C3 + (size_t)h * 64;

  const int qrow = q0 + wave * 16 + l16;
  bf16x8 qf[2];
  qf[0] = *(const bf16x8*)&qkv[base + (size_t)qrow * C3 + quad * 8];
  qf[1] = *(const bf16x8*)&qkv[base + (size_t)qrow * C3 + 32 + quad * 8];

  f32x4 o[4] = {};
  float m_i[4], l_i[4];
#pragma unroll
  for (int r = 0; r < 4; r++) { m_i[r] = NEG; l_i[r] = 0.f; }

  const int ktiles = q0 / 64 + 1;
  for (int kt = 0; kt < ktiles; kt++) {
    const int k0 = kt * 64;
    __syncthreads();
    {
      const int t = tid >> 2, seg = tid & 3;
      const bf16_t* gk = &qkv[base + (size_t)(k0 + t) * C3 + 1024 + seg * 16];
      const bf16_t* gv = &qkv[base + (size_t)(k0 + t) * C3 + 2048 + seg * 16];
      *(bf16x8*)&sK[t * 72 + seg * 16] = *(const bf16x8*)gk;
      *(bf16x8*)&sK[t * 72 + seg * 16 + 8] = *(const bf16x8*)(gk + 8);
      bf16x8 v0 = *(const bf16x8*)gv;
      bf16x8 v1 = *(const bf16x8*)(gv + 8);
#pragma unroll
      for (int i = 0; i < 8; i++) {
        sVt[(seg * 16 + i) * 72 + t] = v0[i];
        sVt[(seg * 16 + 8 + i) * 72 + t] = v1[i];
      }
    }
    __syncthreads();

    f32x4 s[4] = {};
#pragma unroll
    for (int j = 0; j < 4; j++) {
      bf16x8 kf0 = *(const bf16x8*)&sK[(j * 16 + l16) * 72 + quad * 8];
      bf16x8 kf1 = *(const bf16x8*)&sK[(j * 16 + l16) * 72 + 32 + quad * 8];
      s[j] = __builtin_amdgcn_mfma_f32_16x16x32_bf16(qf[0], kf0, s[j], 0, 0, 0);
      s[j] = __builtin_amdgcn_mfma_f32_16x16x32_bf16(qf[1], kf1, s[j], 0, 0, 0);
    }

    const bool masked = (kt == ktiles - 1);
    float mrow[4];
#pragma unroll
    for (int r = 0; r < 4; r++) {
      float mx = m_i[r];
#pragma unroll
      for (int j = 0; j < 4; j++) {
        float v = s[j][r] * 0.125f;
        if (masked) {
          const int kcol = k0 + j * 16 + l16;
          const int qr = q0 + wave * 16 + quad * 4 + r;
          if (kcol > qr) v = NEG;
        }
        s[j][r] = v;
        mx = fmaxf(mx, v);
      }
#pragma unroll
      for (int off = 1; off < 16; off <<= 1) mx = fmaxf(mx, __shfl_xor(mx, off));
      mrow[r] = mx;
    }

#pragma unroll
    for (int r = 0; r < 4; r++) {
      const float alpha = __expf(m_i[r] - mrow[r]);
      m_i[r] = mrow[r];
      float rs = 0.f;
#pragma unroll
      for (int j = 0; j < 4; j++) {
        const float p = __expf(s[j][r] - mrow[r]);
        s[j][r] = p;
        rs += p;
      }
#pragma unroll
      for (int off = 1; off < 16; off <<= 1) rs += __shfl_xor(rs, off);
      l_i[r] = l_i[r] * alpha + rs;
#pragma unroll
      for (int j = 0; j < 4; j++) o[j][r] *= alpha;
    }

    bf16_t* sp = &sP[wave][0];
#pragma unroll
    for (int j = 0; j < 4; j++)
#pragma unroll
      for (int r = 0; r < 4; r++)
        sp[(quad * 4 + r) * 72 + j * 16 + l16] = (bf16_t)s[j][r];
    __syncthreads();

#pragma unroll
    for (int s2 = 0; s2 < 2; s2++) {
      bf16x8 pf = *(const bf16x8*)&sp[l16 * 72 + s2 * 32 + quad * 8];
#pragma unroll
      for (int j = 0; j < 4; j++) {
        bf16x8 vf = *(const bf16x8*)&sVt[(j * 16 + l16) * 72 + s2 * 32 + quad * 8];
        o[j] = __builtin_amdgcn_mfma_f32_16x16x32_bf16(pf, vf, o[j], 0, 0, 0);
      }
    }
  }

#pragma unroll
  for (int j = 0; j < 4; j++) {
#pragma unroll
    for (int r = 0; r < 4; r++) {
      const int row = q0 + wave * 16 + quad * 4 + r;
      const float val = o[j][r] / l_i[r];
      Y[((size_t)b * T + row) * 1024 + h * 64 + j * 16 + l16] = (bf16_t)val;
    }
  }
}

// ---------------------------------------------------------------------------
extern "C" void kernel_launch(void* const* d_in, const int* in_sizes, int n_in,
                              void* d_out, int out_size, void* d_ws,
                              size_t ws_size, hipStream_t stream) {
  // Identify inputs by unique element counts.
  const void* x = nullptr;      // 4194304
  const void* w_qkv = nullptr;  // 3145728
  const void* b_qkv = nullptr;  // 3072
  const void* w_out = nullptr;  // 1048576
  const void* b_out = nullptr;  // 1024
  for (int i = 0; i < n_in; i++) {
    switch (in_sizes[i]) {
      case 4194304: x = d_in[i]; break;
      case 3145728: w_qkv = d_in[i]; break;
      case 3072:    b_qkv = d_in[i]; break;
      case 1048576: w_out = d_in[i]; break;
      case 1024:    b_out = d_in[i]; break;
      default: break;
    }
  }
  float* out = (float*)d_out;  // FP32 output (R6/R7 root-cause)

  int* st = (int*)d_ws;                               // 64 B
  bf16_t* xb = (bf16_t*)((char*)d_ws + 64);           // 4194304
  bf16_t* wqkvT = xb + (size_t)4194304;               // 3145728
  bf16_t* woutT = wqkvT + (size_t)3145728;            // 1048576
  float* bqf = (float*)(woutT + (size_t)1048576);     // 3072 f32
  float* bof = bqf + 3072;                            // 1024 f32
  bf16_t* qkv = (bf16_t*)(bof + 1024);                // 12582912
  bf16_t* Y = qkv + (size_t)12582912;                 // 4194304
  // total ws ~= 48.3 MB (R3 ran fine at 50.4 MB)

  zs_kernel_r7<<<1, 64, 0, stream>>>(st);
  detect3_kernel_r7<<<3, 256, 0, stream>>>(
      (const uint32_t*)x, (const uint32_t*)w_qkv, (const uint32_t*)w_out, st);
  convx_kernel_r7<<<2048, 256, 0, stream>>>(x, xb, 524288, st);
  convbias_kernel_r7<<<12, 256, 0, stream>>>(b_qkv, b_out, bqf, bof, st);
  transconv_kernel_r7<<<dim3(96, 32), 256, 0, stream>>>(w_qkv, wqkvT, 1024,
                                                        3072, st, 1);
  transconv_kernel_r7<<<dim3(32, 32), 256, 0, stream>>>(w_out, woutT, 1024,
                                                        1024, st, 2);
  gemm_bt_kernel_r7<false><<<dim3(24, 32), 256, 0, stream>>>(
      xb, wqkvT, bqf, (void*)qkv, 4096, 3072, 1024);
  attn_kernel_r7<<<dim3(32, 32), 256, 0, stream>>>(qkv, Y);
  gemm_bt_kernel_r7<true><<<dim3(8, 32), 256, 0, stream>>>(
      Y, woutT, bof, (void*)out, 4096, 1024, 1024);
}

// Round 8
// 292.537 us; speedup vs baseline: 1.0286x; 1.0286x over previous
//
#include <hip/hip_runtime.h>
#include <hip/hip_bf16.h>
#include <stdint.h>

// SelfAttention B=2,T=2048,C=1024,H=16,hd=64. Inputs fp32 (bf16-rounded
// values), output FP32 (R7 root-cause). R8: perf round.
//  - attn: sVt XOR-swizzle (conflict-free staging), double-buffered K/V with
//    ONE barrier per k-tile, sP barrier removed (wave-private), LPT reversal.
//  - gemms: m97-style global_load_lds width-16 staging.
// All MFMA fragment layouts byte-identical to the HW-verified R7.

typedef __bf16 bf16_t;
typedef __attribute__((ext_vector_type(8))) __bf16 bf16x8;
typedef __attribute__((ext_vector_type(4))) float f32x4;

static_assert(sizeof(bf16x8) == 16, "bf16x8 must be 16B");

// async global->LDS, 16B/lane. LDS dest = wave-uniform base + lane*16.
__device__ inline void async_copy16(const bf16_t* gsrc, bf16_t* lds_dst) {
  __builtin_amdgcn_global_load_lds(
      (const __attribute__((address_space(1))) uint32_t*)(const void*)gsrc,
      (__attribute__((address_space(3))) uint32_t*)(void*)lds_dst,
      16, 0, 0);
}

// ---------------------------------------------------------------------------
__global__ void zs_kernel(int* st) {
  if (threadIdx.x < 16) st[threadIdx.x] = 0;
}

__global__ __launch_bounds__(256) void detect3_kernel(
    const uint32_t* __restrict__ x, const uint32_t* __restrict__ wq,
    const uint32_t* __restrict__ wo, int* __restrict__ st) {
  __shared__ int cnt[256];
  const uint32_t* p;
  int stride;
  if (blockIdx.x == 0) { p = x;  stride = 1024; }
  else if (blockIdx.x == 1) { p = wq; stride = 768; }
  else { p = wo; stride = 256; }
  int c = 0;
#pragma unroll
  for (int i = 0; i < 8; i++) {
    uint32_t w = p[(size_t)(threadIdx.x * 8 + i) * stride];
    int e = (w >> 7) & 0xff;
    c += (e >= 100 && e <= 134) ? 1 : 0;
  }
  cnt[threadIdx.x] = c;
  __syncthreads();
  for (int s = 128; s > 0; s >>= 1) {
    if (threadIdx.x < s) cnt[threadIdx.x] += cnt[threadIdx.x + s];
    __syncthreads();
  }
  if (threadIdx.x == 0) st[blockIdx.x] = (cnt[0] > 1228) ? 1 : 0;
}

__global__ __launch_bounds__(256) void convx_kernel(
    const void* __restrict__ src, bf16_t* __restrict__ dst, int n8,
    const int* __restrict__ st) {
  const int i = blockIdx.x * 256 + threadIdx.x;
  if (i >= n8) return;
  if (st[0]) {
    ((bf16x8*)dst)[i] = ((const bf16x8*)src)[i];
  } else {
    const float4* s = (const float4*)src;
    float4 a = s[i * 2], b = s[i * 2 + 1];
    bf16x8 o;
    o[0] = (bf16_t)a.x; o[1] = (bf16_t)a.y; o[2] = (bf16_t)a.z; o[3] = (bf16_t)a.w;
    o[4] = (bf16_t)b.x; o[5] = (bf16_t)b.y; o[6] = (bf16_t)b.z; o[7] = (bf16_t)b.w;
    ((bf16x8*)dst)[i] = o;
  }
}

__global__ __launch_bounds__(256) void convbias_kernel(
    const void* __restrict__ bq, const void* __restrict__ bo,
    float* __restrict__ bqf, float* __restrict__ bof,
    const int* __restrict__ st) {
  const int i = blockIdx.x * 256 + threadIdx.x;
  if (i < 3072)
    bqf[i] = st[1] ? (float)((const bf16_t*)bq)[i] : ((const float*)bq)[i];
  if (i < 1024)
    bof[i] = st[2] ? (float)((const bf16_t*)bo)[i] : ((const float*)bo)[i];
}

__global__ __launch_bounds__(256) void transconv_kernel(
    const void* __restrict__ in, bf16_t* __restrict__ out, int R, int C,
    const int* __restrict__ st, int fi) {
  __shared__ bf16_t tile[32][33];
  const int c0 = blockIdx.x * 32, r0 = blockIdx.y * 32;
  const int tx = threadIdx.x & 31;
  const int ty = threadIdx.x >> 5;
  const bool isbf = (st[fi] != 0);
#pragma unroll
  for (int i = 0; i < 4; i++) {
    int r = ty + i * 8;
    size_t idx = (size_t)(r0 + r) * C + c0 + tx;
    tile[r][tx] = isbf ? ((const bf16_t*)in)[idx] : (bf16_t)((const float*)in)[idx];
  }
  __syncthreads();
#pragma unroll
  for (int i = 0; i < 4; i++) {
    int r = ty + i * 8;
    out[(size_t)(c0 + r) * R + r0 + tx] = tile[tx][r];
  }
}

// ---------------------------------------------------------------------------
// C[M,N] = A[M,K] @ Bt[N,K]^T + bias[N]. bf16 in; OUT_F32 selects store type.
// BM=BN=128, BK=32, 4 waves 2x2. m97-style global_load_lds staging.
// ---------------------------------------------------------------------------
template <bool OUT_F32>
__global__ __launch_bounds__(256) void gemm_bt_kernel(
    const bf16_t* __restrict__ A, const bf16_t* __restrict__ Bt,
    const float* __restrict__ bias, void* __restrict__ Cv, int M, int N,
    int K) {
  __shared__ __align__(16) bf16_t sA[128 * 32];
  __shared__ __align__(16) bf16_t sB[128 * 32];
  const int tid = threadIdx.x;
  const int wave = tid >> 6, lane = tid & 63;
  const int quad = lane >> 4, l16 = lane & 15;
  const int wm = (wave >> 1) * 64, wn = (wave & 1) * 64;
  const int bm = blockIdx.y * 128, bn = blockIdx.x * 128;

  // async staging: lane writes LDS at (wave-uniform base) + lane*16B.
  // element offset wave*512 + lane*8 == row (wave*16 + lane>>2), k (lane&3)*8.
  const int srow = wave * 16 + (lane >> 2);
  const int skk = (lane & 3) * 8;
  const bf16_t* gA = A + (size_t)(bm + srow) * K + skk;
  const bf16_t* gB = Bt + (size_t)(bn + srow) * K + skk;
  bf16_t* lA = sA + wave * 512;
  bf16_t* lB = sB + wave * 512;

  f32x4 acc[4][4] = {};

  for (int k0 = 0; k0 < K; k0 += 32) {
    __syncthreads();  // protect LDS from previous iteration's readers
    async_copy16(gA + k0, lA);
    async_copy16(gA + (size_t)64 * K + k0, lA + 2048);
    async_copy16(gB + k0, lB);
    async_copy16(gB + (size_t)64 * K + k0, lB + 2048);
    __syncthreads();  // drains vmcnt -> staging visible

    bf16x8 af[4], bfr[4];
#pragma unroll
    for (int i = 0; i < 4; i++)
      af[i] = *(const bf16x8*)&sA[(wm + i * 16 + l16) * 32 + quad * 8];
#pragma unroll
    for (int j = 0; j < 4; j++)
      bfr[j] = *(const bf16x8*)&sB[(wn + j * 16 + l16) * 32 + quad * 8];
#pragma unroll
    for (int i = 0; i < 4; i++)
#pragma unroll
      for (int j = 0; j < 4; j++)
        acc[i][j] = __builtin_amdgcn_mfma_f32_16x16x32_bf16(af[i], bfr[j],
                                                            acc[i][j], 0, 0, 0);
  }

#pragma unroll
  for (int j = 0; j < 4; j++) {
    const int col = bn + wn + j * 16 + l16;
    const float bv = bias[col];
#pragma unroll
    for (int i = 0; i < 4; i++) {
#pragma unroll
      for (int r = 0; r < 4; r++) {
        const int row = bm + wm + i * 16 + quad * 4 + r;
        const float v = acc[i][j][r] + bv;
        if (OUT_F32)
          ((float*)Cv)[(size_t)row * N + col] = v;
        else
          ((bf16_t*)Cv)[(size_t)row * N + col] = (bf16_t)v;
      }
    }
  }
}

// ---------------------------------------------------------------------------
// MFMA flash attention, causal. R8: double-buffered sK/sVt (1 barrier/tile),
// XOR-swizzled sVt (conflict-free transpose staging), LPT block reversal.
// sVt element (d,t) at d*64 + ((t>>3)^(d>>3))*8 + (t&7).
// ---------------------------------------------------------------------------
__global__ __launch_bounds__(256) void attn_kernel(
    const bf16_t* __restrict__ qkv, bf16_t* __restrict__ Y) {
  constexpr int T = 2048, C3 = 3072;
  constexpr float NEG = -30000.0f;
  __shared__ __align__(16) bf16_t sK[2][64 * 72];
  __shared__ __align__(16) bf16_t sVt[2][64 * 64];
  __shared__ __align__(16) bf16_t sP[4][16 * 72];

  const int tid = threadIdx.x;
  const int wave = tid >> 6, lane = tid & 63;
  const int quad = lane >> 4, l16 = lane & 15;
  const int q0 = (int)(gridDim.x - 1 - blockIdx.x) * 64;  // LPT: heavy first
  const int bh = blockIdx.y;
  const int b = bh >> 4, h = bh & 15;
  const size_t base = (size_t)b * T * C3 + (size_t)h * 64;

  // Q fragments (A-operand): m=l16, k = s2*32 + quad*8 + j
  const int qrow = q0 + wave * 16 + l16;
  const bf16x8 qf0 = *(const bf16x8*)&qkv[base + (size_t)qrow * C3 + quad * 8];
  const bf16x8 qf1 =
      *(const bf16x8*)&qkv[base + (size_t)qrow * C3 + 32 + quad * 8];

  f32x4 o[4] = {};
  float m_i[4], l_i[4];
#pragma unroll
  for (int r = 0; r < 4; r++) { m_i[r] = NEG; l_i[r] = 0.f; }

  // staging mapping: t = tid>>2 (key row), seg = tid&3 (16-elem d chunk)
  const int t = tid >> 2, seg = tid & 3;
  const int tg = t >> 3, tl = t & 7;
  const bf16_t* gK = &qkv[base + (size_t)t * C3 + 1024 + seg * 16];
  const bf16_t* gV = &qkv[base + (size_t)t * C3 + 2048 + seg * 16];

  const int ktiles = q0 / 64 + 1;

  // prologue: tile 0 into registers
  bf16x8 kr0 = *(const bf16x8*)gK;
  bf16x8 kr1 = *(const bf16x8*)(gK + 8);
  bf16x8 vr0 = *(const bf16x8*)gV;
  bf16x8 vr1 = *(const bf16x8*)(gV + 8);

  for (int kt = 0; kt < ktiles; kt++) {
    const int p = kt & 1;
    // stage registers -> LDS buffer p
    *(bf16x8*)&sK[p][t * 72 + seg * 16] = kr0;
    *(bf16x8*)&sK[p][t * 72 + seg * 16 + 8] = kr1;
#pragma unroll
    for (int i = 0; i < 8; i++) {
      const int d = seg * 16 + i;
      sVt[p][d * 64 + ((tg ^ (d >> 3)) << 3) + tl] = vr0[i];
    }
#pragma unroll
    for (int i = 0; i < 8; i++) {
      const int d = seg * 16 + 8 + i;
      sVt[p][d * 64 + ((tg ^ (d >> 3)) << 3) + tl] = vr1[i];
    }
    // prefetch tile kt+1 (overlaps with this tile's compute)
    if (kt + 1 < ktiles) {
      const size_t off = (size_t)(kt + 1) * 64 * C3;
      kr0 = *(const bf16x8*)(gK + off);
      kr1 = *(const bf16x8*)(gK + off + 8);
      vr0 = *(const bf16x8*)(gV + off);
      vr1 = *(const bf16x8*)(gV + off + 8);
    }
    __syncthreads();  // single barrier: staging of p visible; buf 1-p free

    const int k0 = kt * 64;
    // S = Q @ K^T
    f32x4 s[4] = {};
#pragma unroll
    for (int j = 0; j < 4; j++) {
      bf16x8 kf0 = *(const bf16x8*)&sK[p][(j * 16 + l16) * 72 + quad * 8];
      bf16x8 kf1 = *(const bf16x8*)&sK[p][(j * 16 + l16) * 72 + 32 + quad * 8];
      s[j] = __builtin_amdgcn_mfma_f32_16x16x32_bf16(qf0, kf0, s[j], 0, 0, 0);
      s[j] = __builtin_amdgcn_mfma_f32_16x16x32_bf16(qf1, kf1, s[j], 0, 0, 0);
    }

    const bool masked = (kt == ktiles - 1);
    float mrow[4];
#pragma unroll
    for (int r = 0; r < 4; r++) {
      float mx = m_i[r];
#pragma unroll
      for (int j = 0; j < 4; j++) {
        float v = s[j][r] * 0.125f;
        if (masked) {
          const int kcol = k0 + j * 16 + l16;
          const int qr = q0 + wave * 16 + quad * 4 + r;
          if (kcol > qr) v = NEG;
        }
        s[j][r] = v;
        mx = fmaxf(mx, v);
      }
#pragma unroll
      for (int off = 1; off < 16; off <<= 1) mx = fmaxf(mx, __shfl_xor(mx, off));
      mrow[r] = mx;
    }

#pragma unroll
    for (int r = 0; r < 4; r++) {
      const float alpha = __expf(m_i[r] - mrow[r]);
      m_i[r] = mrow[r];
      float rs = 0.f;
#pragma unroll
      for (int j = 0; j < 4; j++) {
        const float pv = __expf(s[j][r] - mrow[r]);
        s[j][r] = pv;
        rs += pv;
      }
#pragma unroll
      for (int off = 1; off < 16; off <<= 1) rs += __shfl_xor(rs, off);
      l_i[r] = l_i[r] * alpha + rs;
#pragma unroll
      for (int j = 0; j < 4; j++) o[j][r] *= alpha;
    }

    // P (C-layout) -> per-wave LDS -> A-layout. Wave-private: no barrier
    // (same-wave DS ordering + compiler lgkmcnt cover the hazard).
    bf16_t* sp = &sP[wave][0];
#pragma unroll
    for (int j = 0; j < 4; j++)
#pragma unroll
      for (int r = 0; r < 4; r++)
        sp[(quad * 4 + r) * 72 + j * 16 + l16] = (bf16_t)s[j][r];

    // O += P @ V (vf from swizzled sVt)
#pragma unroll
    for (int s2 = 0; s2 < 2; s2++) {
      bf16x8 pf = *(const bf16x8*)&sp[l16 * 72 + s2 * 32 + quad * 8];
#pragma unroll
      for (int j = 0; j < 4; j++) {
        const int d = j * 16 + l16;
        const int g = (s2 * 4 + quad) ^ (d >> 3);
        bf16x8 vf = *(const bf16x8*)&sVt[p][d * 64 + g * 8];
        o[j] = __builtin_amdgcn_mfma_f32_16x16x32_bf16(pf, vf, o[j], 0, 0, 0);
      }
    }
  }

#pragma unroll
  for (int j = 0; j < 4; j++) {
#pragma unroll
    for (int r = 0; r < 4; r++) {
      const int row = q0 + wave * 16 + quad * 4 + r;
      const float val = o[j][r] / l_i[r];
      Y[((size_t)b * T + row) * 1024 + h * 64 + j * 16 + l16] = (bf16_t)val;
    }
  }
}

// ---------------------------------------------------------------------------
extern "C" void kernel_launch(void* const* d_in, const int* in_sizes, int n_in,
                              void* d_out, int out_size, void* d_ws,
                              size_t ws_size, hipStream_t stream) {
  const void* x = nullptr;
  const void* w_qkv = nullptr;
  const void* b_qkv = nullptr;
  const void* w_out = nullptr;
  const void* b_out = nullptr;
  for (int i = 0; i < n_in; i++) {
    switch (in_sizes[i]) {
      case 4194304: x = d_in[i]; break;
      case 3145728: w_qkv = d_in[i]; break;
      case 3072:    b_qkv = d_in[i]; break;
      case 1048576: w_out = d_in[i]; break;
      case 1024:    b_out = d_in[i]; break;
      default: break;
    }
  }
  float* out = (float*)d_out;  // FP32 output

  int* st = (int*)d_ws;
  bf16_t* xb = (bf16_t*)((char*)d_ws + 64);
  bf16_t* wqkvT = xb + (size_t)4194304;
  bf16_t* woutT = wqkvT + (size_t)3145728;
  float* bqf = (float*)(woutT + (size_t)1048576);
  float* bof = bqf + 3072;
  bf16_t* qkv = (bf16_t*)(bof + 1024);
  bf16_t* Y = qkv + (size_t)12582912;

  zs_kernel<<<1, 64, 0, stream>>>(st);
  detect3_kernel<<<3, 256, 0, stream>>>(
      (const uint32_t*)x, (const uint32_t*)w_qkv, (const uint32_t*)w_out, st);
  convx_kernel<<<2048, 256, 0, stream>>>(x, xb, 524288, st);
  convbias_kernel<<<12, 256, 0, stream>>>(b_qkv, b_out, bqf, bof, st);
  transconv_kernel<<<dim3(96, 32), 256, 0, stream>>>(w_qkv, wqkvT, 1024, 3072,
                                                     st, 1);
  transconv_kernel<<<dim3(32, 32), 256, 0, stream>>>(w_out, woutT, 1024, 1024,
                                                     st, 2);
  gemm_bt_kernel<false><<<dim3(24, 32), 256, 0, stream>>>(
      xb, wqkvT, bqf, (void*)qkv, 4096, 3072, 1024);
  attn_kernel<<<dim3(32, 32), 256, 0, stream>>>(qkv, Y);
  gemm_bt_kernel<true><<<dim3(8, 32), 256, 0, stream>>>(
      Y, woutT, bof, (void*)out, 4096, 1024, 1024);
}